// Round 3
// baseline (27.997 us; speedup 1.0000x reference)
//
#include <hip/hip_runtime.h>

// Time2Vec: out[b,s, i*64+j] = (j==0) ? (x[b,s,i]*w[i,j]+b[i,j])
//                                     : sin(x[b,s,i]*w[i,j]+b[i,j])
// B=32, S=2048, D=8, E=64  ->  ROWS=65536 rows of 512 f32 outputs.
// Pure write-BW-bound: 134 MB out, 2 MB in. Strategy: coalesced 16B
// nontemporal stores (no L2 write-allocate pollution), w/b hoisted out of
// the loop (channel is loop-invariant per thread), 2-row unroll for ILP.

constexpr int D_IN  = 8;
constexpr int E_PER = 64;
constexpr int CHANS = D_IN * E_PER;      // 512
constexpr int ROWS  = 32 * 2048;         // 65536
constexpr int TOTAL = ROWS * CHANS;      // 33,554,432 (fits int32)

// clang-native vector type: __builtin_nontemporal_store accepts this
// (HIP's float4 is a struct and is rejected).
typedef float vf4 __attribute__((ext_vector_type(4)));

__global__ __launch_bounds__(256) void time2vec_kernel(
    const float* __restrict__ x,      // [ROWS, 8]
    const float* __restrict__ w,      // [8, 64]
    const float* __restrict__ b,      // [8, 64]
    float* __restrict__ out)          // [ROWS, 512]
{
    const int tid      = blockIdx.x * blockDim.x + threadIdx.x;
    const int nthreads = gridDim.x * blockDim.x;   // 524,288; stride % 512 == 0

    // Channel within the 512-wide row is loop-invariant for this thread.
    const int c = (tid * 4) & (CHANS - 1);
    const int i = c >> 6;        // input feature (0..7)
    const int j = c & 63;        // column within the 64-wide embed (multiple of 4)

    const vf4 w4 = *reinterpret_cast<const vf4*>(w + i * E_PER + j);
    const vf4 b4 = *reinterpret_cast<const vf4*>(b + i * E_PER + j);
    const bool lin0 = (j == 0);  // only elem 0 of the vf4 can be the linear col

    const int stride = nthreads * 4;           // 2,097,152 elems = 4096 rows

    // 16 total iterations/thread -> 8 unrolled-by-2 iterations.
    for (int o = tid * 4; o < TOTAL; o += 2 * stride) {
        const int o2   = o + stride;
        const int rowA = o >> 9;
        const int rowB = o2 >> 9;

        // Two independent loads in flight.
        const float xa = x[rowA * D_IN + i];
        const float xb = x[rowB * D_IN + i];

        vf4 ra, rb;
        {
            const float a0 = fmaf(xa, w4.x, b4.x);
            const float a1 = fmaf(xa, w4.y, b4.y);
            const float a2 = fmaf(xa, w4.z, b4.z);
            const float a3 = fmaf(xa, w4.w, b4.w);
            ra.x = lin0 ? a0 : __sinf(a0);
            ra.y = __sinf(a1);
            ra.z = __sinf(a2);
            ra.w = __sinf(a3);
        }
        {
            const float a0 = fmaf(xb, w4.x, b4.x);
            const float a1 = fmaf(xb, w4.y, b4.y);
            const float a2 = fmaf(xb, w4.z, b4.z);
            const float a3 = fmaf(xb, w4.w, b4.w);
            rb.x = lin0 ? a0 : __sinf(a0);
            rb.y = __sinf(a1);
            rb.z = __sinf(a2);
            rb.w = __sinf(a3);
        }

        __builtin_nontemporal_store(ra, reinterpret_cast<vf4*>(out + o));
        if (o2 < TOTAL)
            __builtin_nontemporal_store(rb, reinterpret_cast<vf4*>(out + o2));
    }
}

extern "C" void kernel_launch(void* const* d_in, const int* in_sizes, int n_in,
                              void* d_out, int out_size, void* d_ws, size_t ws_size,
                              hipStream_t stream) {
    const float* x = (const float*)d_in[0];
    const float* w = (const float*)d_in[1];
    const float* b = (const float*)d_in[2];
    float* out = (float*)d_out;

    // 2048 blocks x 256 threads = 524,288 threads -> full 32-wave/CU occupancy.
    dim3 grid(2048), block(256);
    time2vec_kernel<<<grid, block, 0, stream>>>(x, w, b, out);
}